// Round 2
// baseline (291.570 us; speedup 1.0000x reference)
//
#include <hip/hip_runtime.h>
#include <math.h>

static constexpr float kL1   = 0.5f;
static constexpr float kL2   = 1.5f;
static constexpr float kBeta = 50000000.0f;
static constexpr float kEps  = 1e-08f;

__device__ __forceinline__ float waveSum(float v) {
#pragma unroll
    for (int off = 32; off > 0; off >>= 1) v += __shfl_xor(v, off, 64);
    return v;
}

__device__ __forceinline__ float tubeTail(float dot, float pp, float gg) {
    float p_norm = sqrtf(pp);
    float g_norm = sqrtf(gg);
    float denom  = p_norm * g_norm;
    float cosine = (denom == 0.0f) ? 0.0f : dot / denom;
    float s_s    = 1.0f - cosine * cosine;
    float sine   = (s_s < 0.0f) ? 0.0f : sqrtf((s_s <= 0.0f) ? kEps : s_s);
    float gd     = (g_norm == 0.0f) ? (g_norm + kEps) : g_norm;
    float pc     = p_norm * cosine;
    float r_all  = pc / gd;
    float base   = p_norm * sine + fabsf(g_norm - pc);
    float ds     = (r_all >= 1.0f) ? (kL1 * base)
                 : ((r_all >= 0.0f) ? base
                                    : kL2 * fabsf(pc - g_norm - p_norm * sine));
    // -log(tanh(t)) = log(1+e^{-2t}) - log(1-e^{-2t})
    float t  = 1.0f / ds;
    float em = __expf(-2.0f * t);
    return __logf(1.0f + em) - __logf(fmaxf(1.0f - em, 1e-30f));
}

#define ACC3(A, L)                                        \
    dot += A.x*L.x + A.y*L.y + A.z*L.z + A.w*L.w;         \
    pp  += A.x*A.x + A.y*A.y + A.z*A.z + A.w*A.w;         \
    gg  += L.x*L.x + L.y*L.y + L.z*L.z + L.w*L.w;

// One work-unit per wave; straight-line code; no loop-carried vector state.
//   blocks [0, tubeBlocks)                : tube — 1 row-pair per wave
//   blocks [tubeBlocks, +klBlocks)        : KL   — 1 float4-pair per thread (exact fit)
//   blocks [tubeBlocks+klBlocks, end)     : CE   — 1 row per wave
__global__ __launch_bounds__(256) void fused_loss_partials(
    const float* __restrict__ fusion_out, const float* __restrict__ comple_out,
    const float* __restrict__ labels,     const float* __restrict__ labels_enc,
    const float* __restrict__ xA,  const float* __restrict__ xAr,
    const float* __restrict__ xB,  const float* __restrict__ xBr,
    const float* __restrict__ xC,  const float* __restrict__ xCr,
    const float* __restrict__ mu,  const float* __restrict__ logvar,
    float* __restrict__ partials,
    int C, int Z, int tubeBlocks, int klBlocks)
{
    const int lane = threadIdx.x & 63;
    const int wave = threadIdx.x >> 6;
    const int bid  = blockIdx.x;
    constexpr int B = 16384;
    constexpr int D = 512;

    float my = 0.0f;

    if (bid < tubeBlocks) {
        // ---- TUBE: pair t = rows (2t, 2t+1); half-wave h owns row 2t+h ----
        const int t   = bid * 4 + wave;            // [0, 32768)
        const int h   = lane >> 5;
        const int sub = lane & 31;
        const int p   = t >> 13;                   // tensor index (8192 pairs each)
        const int r   = (2 * t) & (B - 1);         // first row of the pair
        const float* ab = (p == 0) ? xAr : (p == 1) ? xBr : (p == 2) ? xCr : comple_out;
        const float* lb = (p == 0) ? xA  : (p == 1) ? xB  : (p == 2) ? xC  : labels_enc;
        const float4* a = (const float4*)(ab + (size_t)r * D) + (h * 128 + sub);
        const float4* l = (const float4*)(lb + (size_t)r * D) + (h * 128 + sub);
        // 8 independent loads, consumed immediately — small live set, full MLP
        float4 A0 = a[0], A1 = a[32], A2 = a[64], A3 = a[96];
        float4 L0 = l[0], L1 = l[32], L2 = l[64], L3 = l[96];
        float dot = 0.0f, pp = 0.0f, gg = 0.0f;
        ACC3(A0, L0); ACC3(A1, L1); ACC3(A2, L2); ACC3(A3, L3);
        // 5-step butterfly within each 32-lane half
#pragma unroll
        for (int off = 16; off > 0; off >>= 1) {
            dot += __shfl_xor(dot, off, 64);
            pp  += __shfl_xor(pp,  off, 64);
            gg  += __shfl_xor(gg,  off, 64);
        }
        // both rows' tails in parallel on the two halves (replicated x32 per half)
        my = tubeTail(dot, pp, gg) * (1.0f / (32.0f * (float)B));
    } else if (bid < tubeBlocks + klBlocks) {
        // ---- KL: exactly one float4 of mu + logvar per thread ----
        const int tid = (bid - tubeBlocks) * 256 + threadIdx.x;   // < B*Z/4 exactly
        const float4 m = ((const float4*)mu)[tid];
        const float4 l = ((const float4*)logvar)[tid];
        float acc = (1.0f + l.x - m.x * m.x - __expf(l.x))
                  + (1.0f + l.y - m.y * m.y - __expf(l.y))
                  + (1.0f + l.z - m.z * m.z - __expf(l.z))
                  + (1.0f + l.w - m.w * m.w - __expf(l.w));
        my = acc * (-0.5f * kBeta / ((float)B * (float)Z));
    } else {
        // ---- CE: one row per wave over C=100 ----
        const int r = (bid - tubeBlocks - klBlocks) * 4 + wave;   // < B
        const float* lrow = labels     + (size_t)r * C;
        const float* frow = fusion_out + (size_t)r * C;
        const bool has0 = (lane < C);
        const bool has1 = (lane + 64 < C);
        float v0 = has0 ? lrow[lane]      : -INFINITY;
        float v1 = has1 ? lrow[lane + 64] : -INFINITY;
        float f0 = has0 ? frow[lane]      : -INFINITY;
        float f1 = has1 ? frow[lane + 64] : -INFINITY;
        float bv; int bi;
        if (v1 > v0) { bv = v1; bi = lane + 64; } else { bv = v0; bi = lane; }
#pragma unroll
        for (int off = 32; off > 0; off >>= 1) {
            float ov = __shfl_xor(bv, off, 64);
            int   oi = __shfl_xor(bi, off, 64);
            if (ov > bv || (ov == bv && oi < bi)) { bv = ov; bi = oi; }
        }
        float m = fmaxf(f0, f1);
#pragma unroll
        for (int off = 32; off > 0; off >>= 1) m = fmaxf(m, __shfl_xor(m, off, 64));
        float e = 0.0f;
        if (has0) e += __expf(f0 - m);
        if (has1) e += __expf(f1 - m);
        e = waveSum(e);
        float tgt = (bi < 64) ? __shfl(f0, bi, 64) : __shfl(f1, bi - 64, 64);
        if (lane == 0) my = -(tgt - m - __logf(e)) / (float)B;
    }

    // ---- block reduce -> per-block partial (no atomics) ----
    float s = waveSum(my);
    __shared__ float sw[4];
    if (lane == 0) sw[wave] = s;
    __syncthreads();
    if (threadIdx.x == 0)
        partials[bid] = sw[0] + sw[1] + sw[2] + sw[3];
}

__global__ __launch_bounds__(256) void reduce_partials(
    const float* __restrict__ partials, float* __restrict__ out, int n)
{
    float s = 0.0f;
    for (int i = threadIdx.x; i < n; i += 256) s += partials[i];
    s = waveSum(s);
    __shared__ float sw[4];
    const int lane = threadIdx.x & 63;
    const int wave = threadIdx.x >> 6;
    if (lane == 0) sw[wave] = s;
    __syncthreads();
    if (threadIdx.x == 0) out[0] = sw[0] + sw[1] + sw[2] + sw[3];
}

extern "C" void kernel_launch(void* const* d_in, const int* in_sizes, int n_in,
                              void* d_out, int out_size, void* d_ws, size_t ws_size,
                              hipStream_t stream) {
    const float* fusion_out = (const float*)d_in[0];
    const float* comple_out = (const float*)d_in[1];
    const float* labels     = (const float*)d_in[2];
    const float* labels_enc = (const float*)d_in[3];
    const float* xA  = (const float*)d_in[4];
    const float* xAr = (const float*)d_in[5];
    const float* xB  = (const float*)d_in[6];
    const float* xBr = (const float*)d_in[7];
    const float* xC  = (const float*)d_in[8];
    const float* xCr = (const float*)d_in[9];
    const float* mu  = (const float*)d_in[10];
    const float* lv  = (const float*)d_in[11];
    float* out = (float*)d_out;
    float* ws  = (float*)d_ws;

    const int B = 16384;
    const int C = in_sizes[0] / B;    // 100
    const int Z = in_sizes[10] / B;   // 128

    const int tubeBlocks = (4 * B / 2) / 4;      // 8192: 1 pair/wave, 4 waves/block
    const int klBlocks   = (B * Z / 4) / 256;    // 2048: 1 float4-pair/thread
    const int ceBlocks   = B / 4;                // 4096: 1 row/wave
    const int totalBlocks = tubeBlocks + klBlocks + ceBlocks;   // 14336

    fused_loss_partials<<<totalBlocks, 256, 0, stream>>>(
        fusion_out, comple_out, labels, labels_enc,
        xA, xAr, xB, xBr, xC, xCr, mu, lv,
        ws, C, Z, tubeBlocks, klBlocks);
    reduce_partials<<<1, 256, 0, stream>>>(ws, out, totalBlocks);
}